// Round 9
// baseline (5609.934 us; speedup 1.0000x reference)
//
#include <hip/hip_runtime.h>
#include <hip/hip_bf16.h>
#include <cstdint>
#include <cstddef>

typedef __hip_bfloat16 bf16;
typedef __bf16 bf16x8 __attribute__((ext_vector_type(8)));
typedef float f32x4 __attribute__((ext_vector_type(4)));

#define BB 2
#define TT 1024
#define CC 1024
#define HH 16
#define PKS 256   // floats per (bh,t) block: k[64] kk[64] bb[64] v[64]
#define LCH 128   // chunk length
#define NCH 8     // chunks per (b,h)

__device__ __forceinline__ bf16 f2b(float v){ return __float2bfloat16(v); }

// quad (4-lane) sum via DPP quad_perm — VALU latency, no DS pipe
__device__ __forceinline__ float quad_add(float x) {
    x += __int_as_float(__builtin_amdgcn_mov_dpp(__float_as_int(x), 0xB1, 0xF, 0xF, true)); // xor 1
    x += __int_as_float(__builtin_amdgcn_mov_dpp(__float_as_int(x), 0x4E, 0xF, 0xF, true)); // xor 2
    return x;
}

// ---------------- batched transpose+convert: f32 [R][S] -> bf16 [S][R] ----------------
struct TrDesc { const float* in; bf16* out; int R, S; };
struct TrArgs { TrDesc d[12]; };

__global__ __launch_bounds__(256) void transpose_batch(TrArgs args)
{
    TrDesc t = args.d[blockIdx.z];
    __shared__ float tile[32][33];
    int s0 = blockIdx.x * 32, r0 = blockIdx.y * 32;
    if (s0 >= t.S || r0 >= t.R) return;      // block-uniform early exit
    int tx = threadIdx.x & 31, ty = threadIdx.x >> 5;
#pragma unroll
    for (int i = 0; i < 4; i++) {
        int r = r0 + ty + i * 8, s = s0 + tx;
        if (r < t.R && s < t.S) tile[ty + i * 8][tx] = t.in[(size_t)r * t.S + s];
    }
    __syncthreads();
#pragma unroll
    for (int i = 0; i < 4; i++) {
        int s = s0 + ty + i * 8, r = r0 + tx;
        if (s < t.S && r < t.R) t.out[(size_t)s * t.R + r] = f2b(tile[tx][ty + i * 8]);
    }
}

// ---------------- token-shift mix (f32 in -> bf16 out) + v_first passthrough ----------------
__global__ __launch_bounds__(256) void mix_kernel(
    const float* __restrict__ x, const float* __restrict__ vfirst,
    const float* __restrict__ mr, const float* __restrict__ mw, const float* __restrict__ mk,
    const float* __restrict__ mv, const float* __restrict__ ma, const float* __restrict__ mg,
    bf16* __restrict__ xr, bf16* __restrict__ xw, bf16* __restrict__ xk,
    bf16* __restrict__ xv, bf16* __restrict__ xa, bf16* __restrict__ xg,
    float* __restrict__ vout)
{
    int row = blockIdx.x;
    int t = row & (TT - 1);
    size_t base = (size_t)row * CC;
    for (int c = threadIdx.x; c < CC; c += 256) {
        float xc = x[base + c];
        float xp = (t > 0) ? x[base - CC + c] : 0.f;
        float d = xp - xc;
        xr[base + c] = f2b(xc + d * mr[c]);
        xw[base + c] = f2b(xc + d * mw[c]);
        xk[base + c] = f2b(xc + d * mk[c]);
        xv[base + c] = f2b(xc + d * mv[c]);
        xa[base + c] = f2b(xc + d * ma[c]);
        xg[base + c] = f2b(xc + d * mg[c]);
        vout[base + c] = vfirst[base + c];   // exact f32 passthrough
    }
}

// ---------------- shared MFMA tile body: 128x128 tile of A[M,K] @ BT[N,K]^T ----------------
template <class EmitF>
__device__ __forceinline__ void gemm_tile(const bf16* __restrict__ A, const bf16* __restrict__ BT,
                                          int K, int m0, int n0, EmitF emit)
{
    __shared__ __align__(16) bf16 Atile[128 * 32];
    __shared__ __align__(16) bf16 Btile[128 * 32];
    int tid = threadIdx.x;
    int w = tid >> 6, lane = tid & 63;
    int wr = w >> 1, wc = w & 1;
    int quad = lane >> 4, l16 = lane & 15;

    f32x4 zero = {0.f, 0.f, 0.f, 0.f};
    f32x4 acc[4][4];
#pragma unroll
    for (int i = 0; i < 4; i++)
#pragma unroll
        for (int j = 0; j < 4; j++) acc[i][j] = zero;

    int rr = lane >> 2;            // 0..15
    int cs = lane & 3;             // chunk slot in LDS
    int ra0 = w * 32 + rr;         // rows this lane stages
    int ra1 = ra0 + 16;
    int cg0 = cs ^ ((ra0 >> 1) & 3);   // global chunk (XOR swizzle)
    int cg1 = cs ^ ((ra1 >> 1) & 3);

    for (int k0 = 0; k0 < K; k0 += 32) {
        uint4 av0 = *reinterpret_cast<const uint4*>(A  + (size_t)(m0 + ra0) * K + k0 + cg0 * 8);
        uint4 av1 = *reinterpret_cast<const uint4*>(A  + (size_t)(m0 + ra1) * K + k0 + cg1 * 8);
        uint4 bv0 = *reinterpret_cast<const uint4*>(BT + (size_t)(n0 + ra0) * K + k0 + cg0 * 8);
        uint4 bv1 = *reinterpret_cast<const uint4*>(BT + (size_t)(n0 + ra1) * K + k0 + cg1 * 8);
        __syncthreads();           // previous tile's reads complete
        *reinterpret_cast<uint4*>(&Atile[ra0 * 32 + cs * 8]) = av0;
        *reinterpret_cast<uint4*>(&Atile[ra1 * 32 + cs * 8]) = av1;
        *reinterpret_cast<uint4*>(&Btile[ra0 * 32 + cs * 8]) = bv0;
        *reinterpret_cast<uint4*>(&Btile[ra1 * 32 + cs * 8]) = bv1;
        __syncthreads();           // staging visible

        bf16x8 af[4], bfr[4];
#pragma unroll
        for (int mi = 0; mi < 4; mi++) {
            int m = wr * 64 + mi * 16 + l16;
            int c2 = quad ^ ((m >> 1) & 3);
            af[mi] = *reinterpret_cast<const bf16x8*>(&Atile[m * 32 + c2 * 8]);
        }
#pragma unroll
        for (int ni = 0; ni < 4; ni++) {
            int n = wc * 64 + ni * 16 + l16;
            int c2 = quad ^ ((n >> 1) & 3);
            bfr[ni] = *reinterpret_cast<const bf16x8*>(&Btile[n * 32 + c2 * 8]);
        }
#pragma unroll
        for (int mi = 0; mi < 4; mi++)
#pragma unroll
            for (int ni = 0; ni < 4; ni++)
                acc[mi][ni] = __builtin_amdgcn_mfma_f32_16x16x32_bf16(af[mi], bfr[ni], acc[mi][ni], 0, 0, 0);
    }

#pragma unroll
    for (int mi = 0; mi < 4; mi++)
#pragma unroll
        for (int ni = 0; ni < 4; ni++)
#pragma unroll
            for (int rg = 0; rg < 4; rg++) {
                int m = m0 + wr * 64 + mi * 16 + quad * 4 + rg;
                int n = n0 + wc * 64 + ni * 16 + l16;
                emit(m, n, acc[mi][ni][rg]);
            }
}

// ---------------- big projections r/k/v: z-batched, N=K=1024, f32 out ----------------
struct B3Args { const bf16* A[3]; const bf16* BT[3]; float* out[3]; };
__global__ __launch_bounds__(256) void big3_kernel(B3Args args)
{
    int z = blockIdx.z;
    float* out = args.out[z];
    gemm_tile(args.A[z], args.BT[z], 1024, blockIdx.x * 128, blockIdx.y * 128,
              [&](int m, int n, float v) { out[(size_t)m * 1024 + n] = v; });
}

// ---------------- lora stage 1: z-batched (different A per z), small N, bf16 out ----------------
struct L1Desc { const bf16* A; const bf16* BT; bf16* outB; int N; int mode; }; // mode: 0 plain, 2 tanh, 3 sigmoid
struct L1Args { L1Desc d[4]; };
__global__ __launch_bounds__(256) void lora1_kernel(L1Args args)
{
    L1Desc dz = args.d[blockIdx.z];
    gemm_tile(dz.A, dz.BT, 1024, blockIdx.x * 128, 0,
              [&](int m, int n, float v) {
                  if (n < dz.N) {
                      float r = (dz.mode == 2) ? tanhf(v)
                              : (dz.mode == 3) ? 1.f / (1.f + expf(-v)) : v;
                      dz.outB[(size_t)m * dz.N + n] = f2b(r);
                  }
              });
}

// ---------------- lora stage 2 (+g2): z-batched, N=1024, f32 out, fused epilogues ----------------
struct L2Desc { const bf16* A; const bf16* BT; const float* bias; float* outF; int K; int mode; };
struct L2Args { L2Desc d[4]; const float* vraw; const float* vfirst; };
__global__ __launch_bounds__(256) void lora2_kernel(L2Args args)
{
    L2Desc dz = args.d[blockIdx.z];
    gemm_tile(dz.A, dz.BT, dz.K, blockIdx.x * 128, blockIdx.y * 128,
              [&](int m, int n, float v) {
                  size_t idx = (size_t)m * 1024 + n;
                  if (dz.mode == 4) {
                      float xx = v + dz.bias[n];
                      float ww = -log1pf(expf(-xx)) - 0.5f;   // -softplus(-x) - 0.5
                      dz.outF[idx] = expf(-expf(ww));
                  } else if (dz.mode == 5) {
                      float xx = v + dz.bias[n];
                      dz.outF[idx] = 1.f / (1.f + expf(-xx));
                  } else if (dz.mode == 6) {
                      float gate = 1.f / (1.f + expf(-(v + dz.bias[n])));
                      float vr = args.vraw[idx];
                      dz.outF[idx] = vr + (args.vfirst[idx] - vr) * gate;
                  } else {
                      dz.outF[idx] = v;
                  }
              });
}

// ---------------- final output projection ----------------
__global__ __launch_bounds__(256) void final_kernel(const bf16* __restrict__ A, const bf16* __restrict__ BT,
                                                    float* __restrict__ out)
{
    gemm_tile(A, BT, 1024, blockIdx.x * 128, blockIdx.y * 128,
              [&](int m, int n, float v) { out[(size_t)m * 1024 + n] = v; });
}

// ---------------- pack: kk norm, k scale -> contiguous PK block per (bh,t) ----------------
// PK[bh][t] block (256 floats): k[0..63], kk[64..127], bb[128..191], v[192..255]
__global__ __launch_bounds__(256) void pack_kernel(
    float* __restrict__ k, const float* __restrict__ a, const float* __restrict__ v,
    const float* __restrict__ kkw, const float* __restrict__ kaw,
    float* __restrict__ PK)
{
    int tid = threadIdx.x;
    int wave = tid >> 6, lane = tid & 63;
    int idx = blockIdx.x * 4 + wave;        // (b*TT+t)*HH + h
    size_t off = (size_t)idx * 64 + lane;
    int c = (idx & 15) * 64 + lane;
    float kraw = k[off];
    float av = a[off];
    float kkv = kraw * kkw[c];
    float s = kkv * kkv;
#pragma unroll
    for (int m = 32; m; m >>= 1) s += __shfl_xor(s, m);
    float kkn = kkv / fmaxf(sqrtf(s), 1e-12f);
    float ks = kraw * (1.f + (av - 1.f) * kaw[c]);
    k[off] = ks;                            // write-back for gn_kernel
    int b = idx >> 14;                      // / (TT*HH)
    int h = idx & 15;
    int t = (idx >> 4) & (TT - 1);
    size_t sidx = (size_t)(b * HH + h) * TT + t;
    float* pw = PK + sidx * PKS;
    pw[lane] = ks; pw[64 + lane] = kkn; pw[128 + lane] = kkn * av; pw[192 + lane] = v[off];
}

// ================= chunked operator scan =================
// Recurrence: S_t = S_{t-1} M_t + v_t k_t^T,  M_t = diag(d_t) - kk_t bb_t^T.
// K1: per chunk c compute P_c = prod M, Q_c = sum v k^T (prod M), and per-step
//     u_t = P^{(t)} r_t, w_t = Q^{(t)} r_t   (so o_t = Sstart_c u_t + w_t).
// K2: Sstart_c = Sstart_{c-1} P_{c-1} + Q_{c-1}  (sequential over 8 chunks, per bh).
// K3: o_t = Sstart_c @ u_t + w_t  (fully parallel).

struct StepOp {
    f32x4 q4[4], d4[4], r4[4], k4[4], b4[4];
    float vi;
};

__device__ __forceinline__ void load_op(StepOp& s, const float* __restrict__ pj,
                                        const float* __restrict__ pr,
                                        const float* __restrict__ pd,
                                        const float* __restrict__ pv)
{
#pragma unroll
    for (int m = 0; m < 4; m++) s.q4[m] = *(const f32x4*)(pj + 64 + 4 * m);   // kk
#pragma unroll
    for (int m = 0; m < 4; m++) s.d4[m] = *(const f32x4*)(pd + 4 * m);        // decay
#pragma unroll
    for (int m = 0; m < 4; m++) s.r4[m] = *(const f32x4*)(pr + 4 * m);        // r
#pragma unroll
    for (int m = 0; m < 4; m++) s.k4[m] = *(const f32x4*)(pj + 4 * m);        // k
#pragma unroll
    for (int m = 0; m < 4; m++) s.b4[m] = *(const f32x4*)(pj + 128 + 4 * m);  // bb
    s.vi = *pv;
}

__device__ __forceinline__ void op_update(const StepOp& sd, float P[16], float Q[16],
                                          float& u, float& w)
{
    float p0 = 0, p1 = 0, p2 = 0, p3 = 0;
    float t0 = 0, t1 = 0, t2 = 0, t3 = 0;
#pragma unroll
    for (int m = 0; m < 4; m++) {
        p0 = fmaf(P[4 * m + 0], sd.q4[m][0], p0);
        p1 = fmaf(P[4 * m + 1], sd.q4[m][1], p1);
        p2 = fmaf(P[4 * m + 2], sd.q4[m][2], p2);
        p3 = fmaf(P[4 * m + 3], sd.q4[m][3], p3);
        t0 = fmaf(Q[4 * m + 0], sd.q4[m][0], t0);
        t1 = fmaf(Q[4 * m + 1], sd.q4[m][1], t1);
        t2 = fmaf(Q[4 * m + 2], sd.q4[m][2], t2);
        t3 = fmaf(Q[4 * m + 3], sd.q4[m][3], t3);
    }
    float saP = -quad_add((p0 + p1) + (p2 + p3));   // row · a, a = -kk
    float saQ = -quad_add((t0 + t1) + (t2 + t3));
#pragma unroll
    for (int m = 0; m < 16; m++) {
        int mm = m >> 2, e = m & 3;
        P[m] = fmaf(saP, sd.b4[mm][e], P[m] * sd.d4[mm][e]);
        Q[m] = fmaf(sd.vi, sd.k4[mm][e], fmaf(saQ, sd.b4[mm][e], Q[m] * sd.d4[mm][e]));
    }
    float u0 = 0, u1 = 0, u2 = 0, u3 = 0;
    float w0 = 0, w1 = 0, w2 = 0, w3 = 0;
#pragma unroll
    for (int m = 0; m < 4; m++) {
        u0 = fmaf(P[4 * m + 0], sd.r4[m][0], u0);
        u1 = fmaf(P[4 * m + 1], sd.r4[m][1], u1);
        u2 = fmaf(P[4 * m + 2], sd.r4[m][2], u2);
        u3 = fmaf(P[4 * m + 3], sd.r4[m][3], u3);
        w0 = fmaf(Q[4 * m + 0], sd.r4[m][0], w0);
        w1 = fmaf(Q[4 * m + 1], sd.r4[m][1], w1);
        w2 = fmaf(Q[4 * m + 2], sd.r4[m][2], w2);
        w3 = fmaf(Q[4 * m + 3], sd.r4[m][3], w3);
    }
    u = quad_add((u0 + u1) + (u2 + u3));
    w = quad_add((w0 + w1) + (w2 + w3));
}

// K1: grid = BB*HH*NCH*4 single-wave blocks (4 waves/CU). Lane (i,q): rows wq*16+i, cols 16q..16q+16.
__global__ __launch_bounds__(64, 1) void opscan_kernel(
    const float* __restrict__ PK, const float* __restrict__ rbuf,
    const float* __restrict__ dbuf,
    float* __restrict__ ubuf, float* __restrict__ wbuf,
    float* __restrict__ Pbuf, float* __restrict__ Qbuf)
{
    const int lane = threadIdx.x;
    const int wq = blockIdx.x & 3;
    const int c  = (blockIdx.x >> 2) & (NCH - 1);
    const int bh = blockIdx.x >> 5;
    const int b = bh >> 4, h = bh & 15;
    const int i = lane >> 2, q = lane & 3;
    const int row = wq * 16 + i, jb = q * 16;

    float P[16], Q[16];
#pragma unroll
    for (int m = 0; m < 16; m++) { P[m] = (jb + m == row) ? 1.f : 0.f; Q[m] = 0.f; }

    const float* pj = PK + ((size_t)bh * TT + c * LCH) * PKS + jb;
    const float* pv = PK + ((size_t)bh * TT + c * LCH) * PKS + 192 + row;
    size_t ebase = ((size_t)b * TT + c * LCH) * CC + h * 64 + jb;
    const float* pr = rbuf + ebase;
    const float* pd = dbuf + ebase;

    float* pu = ubuf + ((size_t)bh * TT + c * LCH) * 64 + row;
    float* pw = wbuf + ((size_t)bh * TT + c * LCH) * 64 + row;

    StepOp A, Bs;
    load_op(A,  pj,       pr,      pd,      pv);
    load_op(Bs, pj + PKS, pr + CC, pd + CC, pv + PKS);

    for (int t = 0; t < LCH; t += 2) {
        float u, w;
        op_update(A, P, Q, u, w);
        if (q == 0) { *pu = u; *pw = w; }
        pu += 64; pw += 64;
        {
            int tn = (t + 2 < LCH) ? t + 2 : LCH - 1;
            load_op(A, pj + (size_t)tn * PKS, pr + (size_t)tn * CC,
                    pd + (size_t)tn * CC, pv + (size_t)tn * PKS);
        }
        __builtin_amdgcn_sched_barrier(0);

        op_update(Bs, P, Q, u, w);
        if (q == 0) { *pu = u; *pw = w; }
        pu += 64; pw += 64;
        {
            int tn = (t + 3 < LCH) ? t + 3 : LCH - 1;
            load_op(Bs, pj + (size_t)tn * PKS, pr + (size_t)tn * CC,
                    pd + (size_t)tn * CC, pv + (size_t)tn * PKS);
        }
        __builtin_amdgcn_sched_barrier(0);
    }

    float* Pg = Pbuf + ((size_t)bh * NCH + c) * 4096 + row * 64 + jb;
    float* Qg = Qbuf + ((size_t)bh * NCH + c) * 4096 + row * 64 + jb;
#pragma unroll
    for (int m = 0; m < 4; m++) {
        *(f32x4*)(Pg + 4 * m) = *(f32x4*)&P[4 * m];
        *(f32x4*)(Qg + 4 * m) = *(f32x4*)&Q[4 * m];
    }
}

// K2: per bh block (256 thr): S=0; for c: store Sstart[c]=S; S = S*P_c + Q_c.
// tid -> i = tid>>2 (row 0..63), q = tid&3 (col-quad). Partials exchanged via LDS in col-halves.
__global__ __launch_bounds__(256) void compose_kernel(
    const float* __restrict__ Pbuf, const float* __restrict__ Qbuf,
    float* __restrict__ Sstart)
{
    __shared__ float Pl[64 * 68];        // row stride 68 (pad)
    __shared__ float part[256 * 36];     // per-thread partials, stride 36 (pad)
    const int tid = threadIdx.x;
    const int bh = blockIdx.x;
    const int i = tid >> 2, q = tid & 3, jb = q * 16;

    float S[16];
#pragma unroll
    for (int m = 0; m < 16; m++) S[m] = 0.f;

    for (int c = 0; c < NCH; c++) {
        float* St = Sstart + ((size_t)bh * NCH + c) * 4096 + i * 64 + jb;
#pragma unroll
        for (int m = 0; m < 4; m++) *(f32x4*)(St + 4 * m) = *(f32x4*)&S[4 * m];

        const float* Pg = Pbuf + ((size_t)bh * NCH + c) * 4096;
#pragma unroll
        for (int e = 0; e < 4; e++) {
            int idx = tid * 16 + e * 4;          // 4 consecutive floats
            f32x4 v4 = *(const f32x4*)(Pg + idx);
            int l = idx >> 6, j = idx & 63;
            *(f32x4*)&Pl[l * 68 + j] = v4;
        }
        const float* Qg = Qbuf + ((size_t)bh * NCH + c) * 4096 + i * 64 + jb;
        __syncthreads();

        float nS[16];
#pragma unroll
        for (int m = 0; m < 16; m++) nS[m] = 0.f;

#pragma unroll
        for (int hh = 0; hh < 2; hh++) {
            f32x4 acc[8];
#pragma unroll
            for (int cc2 = 0; cc2 < 8; cc2++) acc[cc2] = (f32x4){0.f, 0.f, 0.f, 0.f};
#pragma unroll
            for (int m = 0; m < 16; m++) {
                float sv = S[m];
                const float* prow = &Pl[(jb + m) * 68 + 32 * hh];
#pragma unroll
                for (int cc2 = 0; cc2 < 8; cc2++) {
                    int cc = (cc2 + 2 * q) & 7;          // rotate to dodge bank conflicts
                    f32x4 pv4 = *(const f32x4*)(prow + 4 * cc);
                    acc[cc] += pv4 * sv;
                }
            }
            float* pp = &part[tid * 36];
#pragma unroll
            for (int cc2 = 0; cc2 < 8; cc2++) *(f32x4*)(pp + 4 * cc2) = acc[cc2];
            __syncthreads();
            if ((q >> 1) == hh) {                        // this lane's col-slice lives in this half
                int lo = jb - 32 * hh;                   // 0 or 16
#pragma unroll
                for (int m = 0; m < 16; m++) {
                    float s = 0.f;
#pragma unroll
                    for (int qq = 0; qq < 4; qq++)
                        s += part[(i * 4 + qq) * 36 + lo + m];
                    nS[m] = s + Qg[m];
                }
            }
            __syncthreads();
        }
#pragma unroll
        for (int m = 0; m < 16; m++) S[m] = nS[m];
    }
}

// K3: o_t = Sstart_c @ u_t + w_t — data-parallel matvecs, grid = BB*HH*NCH*4 single-wave blocks.
__global__ __launch_bounds__(64, 1) void out_kernel(
    const float* __restrict__ Sstart, const float* __restrict__ ubuf,
    const float* __restrict__ wbuf, float* __restrict__ ybuf)
{
    const int lane = threadIdx.x;
    const int wq = blockIdx.x & 3;
    const int c  = (blockIdx.x >> 2) & (NCH - 1);
    const int bh = blockIdx.x >> 5;
    const int b = bh >> 4, h = bh & 15;
    const int i = lane >> 2, q = lane & 3;
    const int row = wq * 16 + i, jb = q * 16;

    f32x4 S4[4];
    const float* Sg = Sstart + ((size_t)bh * NCH + c) * 4096 + row * 64 + jb;
#pragma unroll
    for (int m = 0; m < 4; m++) S4[m] = *(const f32x4*)(Sg + 4 * m);

    const float* pu = ubuf + ((size_t)bh * TT + c * LCH) * 64 + jb;
    const float* pw = wbuf + ((size_t)bh * TT + c * LCH) * 64 + row;
    float* py = ybuf + ((size_t)b * TT + c * LCH) * CC + h * 64 + row;

    f32x4 U0[4], U1[4];
    float W0, W1;
#pragma unroll
    for (int m = 0; m < 4; m++) U0[m] = *(const f32x4*)(pu + 4 * m);
    W0 = *pw;
#pragma unroll
    for (int m = 0; m < 4; m++) U1[m] = *(const f32x4*)(pu + 64 + 4 * m);
    W1 = pw[64];

    for (int t = 0; t < LCH; t += 2) {
        float x0 = 0, x1 = 0, x2 = 0, x3 = 0;
#pragma unroll
        for (int m = 0; m < 4; m++) {
            x0 = fmaf(S4[m][0], U0[m][0], x0);
            x1 = fmaf(S4[m][1], U0[m][1], x1);
            x2 = fmaf(S4[m][2], U0[m][2], x2);
            x3 = fmaf(S4[m][3], U0[m][3], x3);
        }
        float s = quad_add((x0 + x1) + (x2 + x3));
        if (q == 0) *py = s + W0;
        py += CC;
        {
            int tn = (t + 2 < LCH) ? t + 2 : LCH - 1;
#pragma unroll
            for (int m = 0; m < 4; m++) U0[m] = *(const f32x4*)(pu + (size_t)tn * 64 + 4 * m);
            W0 = pw[(size_t)tn * 64];
        }

        x0 = 0; x1 = 0; x2 = 0; x3 = 0;
#pragma unroll
        for (int m = 0; m < 4; m++) {
            x0 = fmaf(S4[m][0], U1[m][0], x0);
            x1 = fmaf(S4[m][1], U1[m][1], x1);
            x2 = fmaf(S4[m][2], U1[m][2], x2);
            x3 = fmaf(S4[m][3], U1[m][3], x3);
        }
        s = quad_add((x0 + x1) + (x2 + x3));
        if (q == 0) *py = s + W1;
        py += CC;
        {
            int tn = (t + 3 < LCH) ? t + 3 : LCH - 1;
#pragma unroll
            for (int m = 0; m < 4; m++) U1[m] = *(const f32x4*)(pu + (size_t)tn * 64 + 4 * m);
            W1 = pw[(size_t)tn * 64];
        }
    }
}

// ---------------- groupnorm + residual + gate -> z (bf16), 4 heads/block ----------------
__global__ __launch_bounds__(256) void gn_kernel(
    const float* __restrict__ y, const float* __restrict__ r, const float* __restrict__ k,
    const float* __restrict__ v, const float* __restrict__ g,
    const float* __restrict__ lnw, const float* __restrict__ lnb,
    const float* __restrict__ rk, bf16* __restrict__ z)
{
    int tid = threadIdx.x;
    int idx = blockIdx.x * 4 + (tid >> 6);   // (b*T+t)*16 + h
    int lane = tid & 63;
    size_t off = (size_t)idx * 64 + lane;
    int c = (idx & 15) * 64 + lane;
    float yv = y[off];
    float rv = r[off], kv = k[off], vv = v[off];
    float s1 = yv, s2 = yv * yv, s3 = rv * kv * rk[c];
#pragma unroll
    for (int m = 32; m; m >>= 1) {
        s1 += __shfl_xor(s1, m);
        s2 += __shfl_xor(s2, m);
        s3 += __shfl_xor(s3, m);
    }
    float mu = s1 * (1.f / 64.f);
    float var = fmaxf(s2 * (1.f / 64.f) - mu * mu, 0.f);
    float yn = (yv - mu) * rsqrtf(var + 64e-5f) * lnw[c] + lnb[c];
    float out = (yn + s3 * vv) * g[off];
    z[off] = f2b(out);
}

// ---------------- host ----------------
extern "C" void kernel_launch(void* const* d_in, const int* in_sizes, int n_in,
                              void* d_out, int out_size, void* d_ws, size_t ws_size,
                              hipStream_t stream)
{
    const float* x       = (const float*)d_in[0];
    const float* v_first = (const float*)d_in[1];
    const float* x_r = (const float*)d_in[2];
    const float* x_w = (const float*)d_in[3];
    const float* x_k = (const float*)d_in[4];
    const float* x_v = (const float*)d_in[5];
    const float* x_a = (const float*)d_in[6];
    const float* x_g = (const float*)d_in[7];
    const float* w1 = (const float*)d_in[8];
    const float* w2 = (const float*)d_in[9];
    const float* w0 = (const float*)d_in[10];
    const float* a1 = (const float*)d_in[11];
    const float* a2 = (const float*)d_in[12];
    const float* a0 = (const float*)d_in[13];
    const float* v1 = (const float*)d_in[14];
    const float* v2 = (const float*)d_in[15];
    const float* v0 = (const float*)d_in[16];
    const float* g1 = (const float*)d_in[17];
    const float* g2 = (const float*)d_in[18];
    const float* k_k = (const float*)d_in[19];
    const float* k_a = (const float*)d_in[20];
    const float* r_k = (const float*)d_in[21];
    const float* W_r = (const float*)d_in[22];
    const float* W_k = (const float*)d_in[23];
    const float* W_v = (const float*)d_in[24];
    const float* W_o = (const float*)d_in[25];
    const float* ln_w = (const float*)d_in[26];
    const float* ln_b = (const float*)d_in[27];

    const size_t BTC = (size_t)BB * TT * CC;   // 2M
    const int M = BB * TT;                     // 2048

    char* ws = (char*)d_ws;
    size_t off = 0;
    auto alloc = [&](size_t bytes) -> char* {
        char* p = ws + off;
        off += (bytes + 255) & ~(size_t)255;
        return p;
    };

    // ---- region0: everything here is dead before pack_kernel; PK aliases it ----
    bf16* xr = (bf16*)alloc(BTC * 2);
    bf16* xw = (bf16*)alloc(BTC * 2);
    bf16* xk = (bf16*)alloc(BTC * 2);
    bf16* xv = (bf16*)alloc(BTC * 2);
    bf16* xa = (bf16*)alloc(BTC * 2);
    bf16* xg = (bf16*)alloc(BTC * 2);
    bf16* WrT = (bf16*)alloc(1024 * 1024 * 2);
    bf16* WkT = (bf16*)alloc(1024 * 1024 * 2);
    bf16* WvT = (bf16*)alloc(1024 * 1024 * 2);
    bf16* w1T = (bf16*)alloc(128 * 1024 * 2);   // 64 rows used, pad benign
    bf16* a1T = (bf16*)alloc(128 * 1024 * 2);
    bf16* v1T = (bf16*)alloc(128 * 1024 * 2);   // 32 rows used
    bf16* g1T = (bf16*)alloc(128 * 1024 * 2);
    bf16* w2T = (bf16*)alloc(1024 * 64 * 2);
    bf16* a2T = (bf16*)alloc(1024 * 64 * 2);
    bf16* v2T = (bf16*)alloc(1024 * 32 * 2);
    bf16* g2T = (bf16*)alloc(1024 * 128 * 2);
    bf16* h_w = (bf16*)alloc((size_t)M * 64 * 2);
    bf16* h_a = (bf16*)alloc((size_t)M * 64 * 2);
    bf16* h_v = (bf16*)alloc((size_t)M * 32 * 2);
    bf16* h_g = (bf16*)alloc((size_t)M * 128 * 2);

    // PK aliases region0 (32 MB); continue past max(region0, PK)
    float* PK = (float*)ws;
    size_t pk_end = (size_t)BB * HH * TT * PKS * 4;   // 33,554,432
    if (off < pk_end) off = pk_end;
    off = (off + 255) & ~(size_t)255;

    // ---- live across pack/scan ----
    bf16* WoT = (bf16*)alloc(1024 * 1024 * 2);
    float* rbuf = (float*)alloc(BTC * 4);
    float* kbuf = (float*)alloc(BTC * 4);
    float* vraw = (float*)alloc(BTC * 4);   // reused as ybuf after lora2
    float* vbuf = (float*)alloc(BTC * 4);
    float* dbuf = (float*)alloc(BTC * 4);   // reused as zbuf (bf16) after scan chain
    float* abuf = (float*)alloc(BTC * 4);   // reused as ubuf after pack
    float* gbuf = (float*)alloc(BTC * 4);
    float* wbuf = (float*)alloc((size_t)BB * HH * TT * 64 * 4);   // 8 MB
    float* Pbuf = (float*)alloc((size_t)BB * HH * NCH * 4096 * 4); // 4 MB
    float* Qbuf = (float*)alloc((size_t)BB * HH * NCH * 4096 * 4); // 4 MB
    float* Sst  = (float*)alloc((size_t)BB * HH * NCH * 4096 * 4); // 4 MB

    float* ybuf = vraw;
    bf16*  zbuf = (bf16*)dbuf;
    float* ubuf = abuf;        // alias: abuf dead after pack_kernel

    (void)in_sizes; (void)n_in; (void)out_size; (void)ws_size;

    // 1) all weight transposes in one launch
    TrArgs ta;
    ta.d[0]  = {W_r, WrT, 1024, 1024};
    ta.d[1]  = {W_k, WkT, 1024, 1024};
    ta.d[2]  = {W_v, WvT, 1024, 1024};
    ta.d[3]  = {W_o, WoT, 1024, 1024};
    ta.d[4]  = {w1, w1T, 1024, 64};
    ta.d[5]  = {a1, a1T, 1024, 64};
    ta.d[6]  = {v1, v1T, 1024, 32};
    ta.d[7]  = {g1, g1T, 1024, 128};
    ta.d[8]  = {w2, w2T, 64, 1024};
    ta.d[9]  = {a2, a2T, 64, 1024};
    ta.d[10] = {v2, v2T, 32, 1024};
    ta.d[11] = {g2, g2T, 128, 1024};
    transpose_batch<<<dim3(32, 32, 12), 256, 0, stream>>>(ta);

    // 2) token-shift mix (+ v_first passthrough)
    float* vout = (float*)d_out + BTC;
    mix_kernel<<<BB * TT, 256, 0, stream>>>(x, v_first, x_r, x_w, x_k, x_v, x_a, x_g,
                                            xr, xw, xk, xv, xa, xg, vout);

    // 3) big projections r/k/v
    B3Args b3;
    b3.A[0] = xr; b3.A[1] = xk; b3.A[2] = xv;
    b3.BT[0] = WrT; b3.BT[1] = WkT; b3.BT[2] = WvT;
    b3.out[0] = rbuf; b3.out[1] = kbuf; b3.out[2] = vraw;
    big3_kernel<<<dim3(16, 8, 3), 256, 0, stream>>>(b3);

    // 4) lora stage 1
    L1Args l1;
    l1.d[0] = {xw, w1T, h_w, 64, 2};
    l1.d[1] = {xa, a1T, h_a, 64, 0};
    l1.d[2] = {xv, v1T, h_v, 32, 0};
    l1.d[3] = {xg, g1T, h_g, 128, 3};
    lora1_kernel<<<dim3(16, 1, 4), 256, 0, stream>>>(l1);

    // 5) lora stage 2 + g2
    L2Args l2;
    l2.d[0] = {h_w, w2T, w0, dbuf, 64, 4};
    l2.d[1] = {h_a, a2T, a0, abuf, 64, 5};
    l2.d[2] = {h_v, v2T, v0, vbuf, 32, 6};
    l2.d[3] = {h_g, g2T, nullptr, gbuf, 128, 0};
    l2.vraw = vraw; l2.vfirst = v_first;
    lora2_kernel<<<dim3(16, 8, 4), 256, 0, stream>>>(l2);

    // 6) pack (PK blocks {k,kk,bb,v}; writes scaled k back to kbuf)
    pack_kernel<<<BB * TT * HH / 4, 256, 0, stream>>>(kbuf, abuf, vbuf, k_k, k_a, PK);

    // 7) chunked operator scan: K1 operators+u/w, K2 compose, K3 outputs
    opscan_kernel<<<BB * HH * NCH * 4, 64, 0, stream>>>(PK, rbuf, dbuf, ubuf, wbuf, Pbuf, Qbuf);
    compose_kernel<<<BB * HH, 256, 0, stream>>>(Pbuf, Qbuf, Sst);
    out_kernel<<<BB * HH * NCH * 4, 64, 0, stream>>>(Sst, ubuf, wbuf, ybuf);

    // 8) groupnorm + residual + gate (writes zbuf = dbuf region)
    gn_kernel<<<BB * TT * HH / 4, 256, 0, stream>>>(ybuf, rbuf, kbuf, vbuf, gbuf, ln_w, ln_b, r_k, zbuf);

    // 9) output projection -> d_out (f32)
    final_kernel<<<dim3(16, 8), 256, 0, stream>>>(zbuf, WoT, (float*)d_out);
}